// Round 1
// baseline (133.659 us; speedup 1.0000x reference)
//
#include <hip/hip_runtime.h>

typedef unsigned short u16;
typedef unsigned int u32;
typedef __attribute__((ext_vector_type(8))) __bf16 bf16x8;
typedef __attribute__((ext_vector_type(8))) unsigned short u16x8;
typedef __attribute__((ext_vector_type(4))) float f32x4;

// ---- bf16 <-> f32 (RNE), bit-exact storage as u16 ----
__device__ __forceinline__ u16 f2bf(float f) {
  u32 u = __builtin_bit_cast(u32, f);
  u += 0x7FFFu + ((u >> 16) & 1u);
  return (u16)(u >> 16);
}
__device__ __forceinline__ float bf2f(u16 h) {
  u32 u = ((u32)h) << 16;
  return __builtin_bit_cast(float, u);
}

// in-register butterfly set over 16 elements, pair mask M
template <int M>
__device__ __forceinline__ void bfly16(float r[16]) {
#pragma unroll
  for (int j = 0; j < 16; ++j)
    if ((j & M) == 0) {
      float a = r[j], b = r[j | M];
      r[j] = a + b;
      r[j | M] = a - b;
    }
}

// ---- K0: conv_w fp32 -> bf16 (Wcat[256][128], rows = p*128+o) ----
__global__ __launch_bounds__(256) void k0_wcat(const float* __restrict__ cw,
                                               u16* __restrict__ wc) {
  int i = blockIdx.x * 256 + threadIdx.x;  // grid = exactly 32768 threads
  wc[i] = f2bf(cw[i]);
}

// ---- K1: per (b,c) plane: pad + 2D FWHT -> f2[b][c][h*64+w] bf16 ----
__global__ __launch_bounds__(256) void k1_fwht(const float* __restrict__ x,
                                               u16* __restrict__ f2) {
  __shared__ float lds[64 * 68];  // padded stride 68 floats (272B, 16B-aligned rows)
  const int t = threadIdx.x;
  const size_t bc = blockIdx.x;
  const float* xp = x + bc * 3136;
  float r[16];
  // phase A ownership: h = t>>2, w = (t&3)*16 + i
  const int hA = t >> 2, wq = t & 3;
  const bool hok = hA < 56;
#pragma unroll
  for (int c4 = 0; c4 < 4; ++c4) {
    const int w0 = wq * 16 + c4 * 4;
    if (hok && w0 < 56) {
      const float4 v4 = *(const float4*)(xp + hA * 56 + w0);
      r[c4 * 4 + 0] = v4.x; r[c4 * 4 + 1] = v4.y;
      r[c4 * 4 + 2] = v4.z; r[c4 * 4 + 3] = v4.w;
    } else {
      r[c4 * 4 + 0] = 0.f; r[c4 * 4 + 1] = 0.f;
      r[c4 * 4 + 2] = 0.f; r[c4 * 4 + 3] = 0.f;
    }
  }
  // w-stages 1,2,4,8 (16 consecutive w in regs)
  bfly16<1>(r); bfly16<2>(r); bfly16<4>(r); bfly16<8>(r);
#pragma unroll
  for (int c4 = 0; c4 < 4; ++c4)
    *(float4*)&lds[hA * 68 + wq * 16 + c4 * 4] =
        make_float4(r[c4 * 4 + 0], r[c4 * 4 + 1], r[c4 * 4 + 2], r[c4 * 4 + 3]);
  __syncthreads();
  // phase B ownership: h = 4*(t>>4)+d, w = 16*k + (t&15); idx = 4k+d
  const int hg = t >> 4, rB = t & 15;
  float q[16];
#pragma unroll
  for (int k = 0; k < 4; ++k)
#pragma unroll
    for (int d = 0; d < 4; ++d)
      q[k * 4 + d] = lds[(hg * 4 + d) * 68 + k * 16 + rB];
  bfly16<4>(q);  // w stage 16 (k^1)
  bfly16<8>(q);  // w stage 32 (k^2)
  bfly16<1>(q);  // h stage 1  (d^1)
  bfly16<2>(q);  // h stage 2  (d^2)
#pragma unroll
  for (int k = 0; k < 4; ++k)
#pragma unroll
    for (int d = 0; d < 4; ++d)
      lds[(hg * 4 + d) * 68 + k * 16 + rB] = q[k * 4 + d];  // own addrs: no barrier needed before
  __syncthreads();
  // phase C ownership: h = 4j + (t>>6), w = t&63
  const int wC = t & 63, rr = t >> 6;
  float s[16];
#pragma unroll
  for (int j = 0; j < 16; ++j) s[j] = lds[(4 * j + rr) * 68 + wC];
  bfly16<1>(s); bfly16<2>(s); bfly16<4>(s); bfly16<8>(s);  // h stages 4,8,16,32
  u16* dst = f2 + (bc << 12);
#pragma unroll
  for (int j = 0; j < 16; ++j) dst[(4 * j + rr) * 64 + wC] = f2bf(s[j]);
}

// ---- K2: per (b, 64-pos tile): GEMM (Wcat[256x128] @ f2) + v-scale +
//          soft-threshold + p-sum, IN-PLACE on f2 -> g[b][o][pos] ----
__global__ __launch_bounds__(256) void k2_mix(u16* __restrict__ fg,
                                              const u16* __restrict__ wc,
                                              const float* __restrict__ vv,
                                              const float* __restrict__ tt) {
  __shared__ u16 bt[64 * 136];  // [pos][c], row stride 136 (272B) -> balanced b128 reads
  const int t = threadIdx.x;
  const int b = blockIdx.x >> 6;
  const int p0 = (blockIdx.x & 63) << 6;
  u16* fb = fg + ((size_t)b << 19);
  // stage B-tile transposed: thread t: c = 2*(t&63), 2*(t&63)+1 ; pos = 16*(t>>6)..+15
  {
    const int c2 = t & 63, pq = t >> 6;
    const u16* s0 = fb + ((size_t)(2 * c2) << 12) + p0 + 16 * pq;
    u16x8 a0 = *(const u16x8*)(s0);
    u16x8 a1 = *(const u16x8*)(s0 + 8);
    u16x8 b0 = *(const u16x8*)(s0 + 4096);
    u16x8 b1 = *(const u16x8*)(s0 + 4096 + 8);
#pragma unroll
    for (int e = 0; e < 8; ++e)
      *(u32*)&bt[(16 * pq + e) * 136 + 2 * c2] = (u32)a0[e] | ((u32)b0[e] << 16);
#pragma unroll
    for (int e = 0; e < 8; ++e)
      *(u32*)&bt[(16 * pq + 8 + e) * 136 + 2 * c2] = (u32)a1[e] | ((u32)b1[e] << 16);
  }
  __syncthreads();
  const int wv = t >> 6, l = t & 63, lr = l & 15, lq = l >> 4;
  f32x4 acc[2][2][4] = {};  // [p][fm(o 16-chunk)][fn(pos 16-chunk)]
#pragma unroll
  for (int q = 0; q < 4; ++q) {  // K chunks of 32
    bf16x8 af[2][2];
#pragma unroll
    for (int fp = 0; fp < 2; ++fp)
#pragma unroll
      for (int fm = 0; fm < 2; ++fm) {
        const int row = fp * 128 + wv * 32 + fm * 16 + lr;  // A row = lane&15
        af[fp][fm] = __builtin_bit_cast(
            bf16x8, *(const u16x8*)(wc + row * 128 + 32 * q + 8 * lq));
      }
#pragma unroll
    for (int fn = 0; fn < 4; ++fn) {
      const bf16x8 bq = __builtin_bit_cast(
          bf16x8, *(const u16x8*)&bt[(fn * 16 + lr) * 136 + 32 * q + 8 * lq]);
#pragma unroll
      for (int fp = 0; fp < 2; ++fp)
#pragma unroll
        for (int fm = 0; fm < 2; ++fm)
          acc[fp][fm][fn] = __builtin_amdgcn_mfma_f32_16x16x32_bf16(
              af[fp][fm], bq, acc[fp][fm][fn], 0, 0, 0);
    }
  }
  // epilogue: f4 = v_p * acc ; soft-threshold ; sum over p ; write bf16 in-place
#pragma unroll
  for (int fn = 0; fn < 4; ++fn) {
    const int pos = p0 + fn * 16 + lr;  // D col = lane&15
    const float v0 = vv[pos], v1 = vv[4096 + pos];
    const float t0 = fmaxf(tt[pos], 0.f), t1 = fmaxf(tt[4096 + pos], 0.f);
#pragma unroll
    for (int fm = 0; fm < 2; ++fm)
#pragma unroll
      for (int rg = 0; rg < 4; ++rg) {  // D row = 4*(lane>>4)+rg
        const float z0 = v0 * acc[0][fm][fn][rg];
        const float z1 = v1 * acc[1][fm][fn][rg];
        const float s0v = copysignf(fmaxf(fabsf(z0) - t0, 0.f), z0);
        const float s1v = copysignf(fmaxf(fabsf(z1) - t1, 0.f), z1);
        const int o = wv * 32 + fm * 16 + lq * 4 + rg;
        fb[(size_t)o * 4096 + pos] = f2bf(s0v + s1v);
      }
  }
}

// ---- K3: per (b,o) plane: 2D IWHT (x 1/4096) + crop + residual add ----
__global__ __launch_bounds__(256) void k3_iwht(const u16* __restrict__ g,
                                               const float* __restrict__ x,
                                               float* __restrict__ y) {
  __shared__ float lds[64 * 68];
  const int t = threadIdx.x;
  const size_t bo = blockIdx.x;
  const u16* gp = g + (bo << 12);
  float r[16];
  const int hA = t >> 2, wq = t & 3;
  {
    u16x8 a0 = *(const u16x8*)(gp + hA * 64 + wq * 16);
    u16x8 a1 = *(const u16x8*)(gp + hA * 64 + wq * 16 + 8);
#pragma unroll
    for (int e = 0; e < 8; ++e) {
      r[e] = bf2f(a0[e]);
      r[8 + e] = bf2f(a1[e]);
    }
  }
  bfly16<1>(r); bfly16<2>(r); bfly16<4>(r); bfly16<8>(r);
#pragma unroll
  for (int c4 = 0; c4 < 4; ++c4)
    *(float4*)&lds[hA * 68 + wq * 16 + c4 * 4] =
        make_float4(r[c4 * 4 + 0], r[c4 * 4 + 1], r[c4 * 4 + 2], r[c4 * 4 + 3]);
  __syncthreads();
  const int hg = t >> 4, rB = t & 15;
  float q[16];
#pragma unroll
  for (int k = 0; k < 4; ++k)
#pragma unroll
    for (int d = 0; d < 4; ++d)
      q[k * 4 + d] = lds[(hg * 4 + d) * 68 + k * 16 + rB];
  bfly16<4>(q); bfly16<8>(q); bfly16<1>(q); bfly16<2>(q);
#pragma unroll
  for (int k = 0; k < 4; ++k)
#pragma unroll
    for (int d = 0; d < 4; ++d)
      lds[(hg * 4 + d) * 68 + k * 16 + rB] = q[k * 4 + d];
  __syncthreads();
  const int wC = t & 63, rr = t >> 6;
  float s[16];
#pragma unroll
  for (int j = 0; j < 16; ++j) s[j] = lds[(4 * j + rr) * 68 + wC];
  bfly16<1>(s); bfly16<2>(s); bfly16<4>(s); bfly16<8>(s);
  if (wC < 56) {
#pragma unroll
    for (int j = 0; j < 14; ++j) {  // h = 4j+rr <= 55
      const int h = 4 * j + rr;
      const size_t idx = bo * 3136 + (size_t)(h * 56 + wC);
      y[idx] = x[idx] + s[j] * (1.f / 4096.f);
    }
  }
}

extern "C" void kernel_launch(void* const* d_in, const int* in_sizes, int n_in,
                              void* d_out, int out_size, void* d_ws, size_t ws_size,
                              hipStream_t stream) {
  const float* x = (const float*)d_in[0];
  const float* cw = (const float*)d_in[1];
  const float* v = (const float*)d_in[2];
  const float* T = (const float*)d_in[3];
  float* y = (float*)d_out;

  u16* f2 = (u16*)d_ws;                               // 64*128*4096 bf16 = 67,108,864 B
  u16* wcat = (u16*)((char*)d_ws + 67108864);         // 2*128*128 bf16 = 65,536 B

  k0_wcat<<<128, 256, 0, stream>>>(cw, wcat);
  k1_fwht<<<8192, 256, 0, stream>>>(x, f2);
  k2_mix<<<4096, 256, 0, stream>>>(f2, wcat, v, T);
  k3_iwht<<<8192, 256, 0, stream>>>(f2, x, y);
}